// Round 6
// baseline (699.845 us; speedup 1.0000x reference)
//
#include <hip/hip_runtime.h>
#include <hip/hip_bf16.h>
#include <hip/hip_cooperative_groups.h>

namespace cg = cooperative_groups;

#define N_NODES 20000
#define N_EDGES 320000
#define F_IN    128
#define F_HID   32
#define NHEAD   8
#define FDIM    256   // NHEAD * D (layer-1 feat width)
#define CAP     96    // max in-degree capacity; P(Poisson(16) > 96) ~ 1e-44

// two-level partition params
#define GROUPS  313   // ceil(N_NODES/64): coarse bin = dst>>6 (64 nodes per group)
#define GPAD    16    // gcnt padded to 1 counter per 64B line
#define GCAP    2048  // per-group record capacity
#define EPB     4096  // edges per P1 task (16 per thread)
#define P1B     ((N_EDGES + EPB - 1) / EPB)   // 79
#define GEMMB   (N_NODES / 16)                // 1250
#define L1T     (N_NODES / 4)                 // 5000 tasks (4 nodes each)

#define TW2     12    // l2 t_w stride (floats): 48B rows, 16B-aligned for b128

// LDS union (bytes): S1-P1 18952 | S1-GEMM 1024 | S2 24832 | S3 20224 | S4 20096
#define SMEM_BYTES 24832

typedef __hip_bfloat16 bf16;
typedef __attribute__((ext_vector_type(8))) short short8;
typedef __attribute__((ext_vector_type(4))) float f32x4;

__device__ __forceinline__ unsigned short f2bf_rne(float f){
  unsigned u = __float_as_uint(f);
  unsigned r = u + 0x7FFFu + ((u >> 16) & 1u);
  return (unsigned short)(r >> 16);
}
__device__ __forceinline__ float bf2f(unsigned short s){
  return __uint_as_float((unsigned)s << 16);
}

struct Prm {
  const float* x; const int* src; const int* dst;
  const float* W1; const float* al1; const float* ar1; const float* b1;
  const float* W2; const float* al2; const float* ar2; const float* b2;
  float* out;
  unsigned short* feat; float* el1; float* er1; float* el2; float* er2;
  int* cnt; int* bucket; unsigned short* hbf;
  unsigned short* W1th; unsigned short* W1tl; float* q_lt; float* q_rt;
  int* gcnt; unsigned* recs;
};

// ============ ONE COOPERATIVE KERNEL, 5 stages, 4 grid syncs ============
// Round-6 rationale: 2 rounds of blind per-kernel attribution failed (all
// stages model fast, dur stays ~170). Merge everything: removes 4 dispatch
// boundaries (launch gap + full drain/ramp each), and makes our entire GPU
// work ONE rocprof row that outranks the harness's 44us poison fills ->
// real counters next round. Stage bodies are verbatim round-5 arithmetic.
__global__ __launch_bounds__(256, 6) void gat_coop(Prm p)
{
  __shared__ __align__(16) char smem[SMEM_BYTES];
  const int tid  = threadIdx.x;
  const int nb   = gridDim.x;
  cg::grid_group gg = cg::this_grid();

  // ---------------- S0: init (gcnt=0, W1 transpose+split, q projections) ----------------
  for (int vb = blockIdx.x; vb < 130; vb += nb){
    if (vb == 0){
      for (int i = tid; i < GROUPS*GPAD; i += 256) p.gcnt[i] = 0;
    } else if (vb < 129){
      int i = (vb - 1)*256 + tid;   // over FDIM*F_IN
      int n = i >> 7, k = i & 127;
      float v = p.W1[(size_t)k*FDIM + n];
      unsigned short hs = f2bf_rne(v);
      p.W1th[i] = hs;
      p.W1tl[i] = f2bf_rne(v - bf2f(hs));
    } else {
      int t = tid;                  // t = k*8 + hh
      int k = t >> 3, hh = t & 7;
      float sl = 0.f, sr = 0.f;
      #pragma unroll
      for (int d = 0; d < 32; d++){
        float w = p.W2[(size_t)k*FDIM + hh*32 + d];
        sl = fmaf(w, p.al2[hh*32 + d], sl);
        sr = fmaf(w, p.ar2[hh*32 + d], sr);
      }
      p.q_lt[t] = sl;   // layout [k][hh]
      p.q_rt[t] = sr;
    }
  }
  gg.sync();

  // ---------------- S1: P1 counting-sort partition + MFMA GEMM ----------------
  for (int vb = blockIdx.x; vb < P1B + GEMMB; vb += nb){
    __syncthreads();   // LDS handoff between loop iterations
    if (vb < P1B){
      int* hist     = (int*)smem;              // 313
      int* prefix   = hist + GROUPS;           // 313
      int* chunktot = prefix + GROUPS;         // 16
      unsigned* sorted = (unsigned*)(chunktot + 16);   // 4096 (16 KB)

      for (int t = tid; t < GROUPS; t += 256) hist[t] = 0;
      __syncthreads();

      const int e0 = vb * EPB;
      const int nval = min(EPB, N_EDGES - e0);
      for (int k = 0; k < EPB/256; k++){
        int i = e0 + k*256 + tid;
        if (i < N_EDGES) atomicAdd(&hist[p.dst[i] >> 6], 1);
      }
      __syncthreads();
      if (tid < 16){
        int base = tid*20, run = 0;
        for (int c = 0; c < 20; c++){
          int t = base + c;
          if (t < GROUPS){ prefix[t] = run; run += hist[t]; }
        }
        chunktot[tid] = run;
      }
      __syncthreads();
      if (tid == 0){
        int run = 0;
        #pragma unroll
        for (int c = 0; c < 16; c++){ int t = chunktot[c]; chunktot[c] = run; run += t; }
      }
      __syncthreads();
      for (int t = tid; t < GROUPS; t += 256) prefix[t] += chunktot[t/20];
      __syncthreads();
      {
        const int rot = (vb * 97) % GROUPS;   // de-convoy
        for (int tt = tid; tt < GROUPS; tt += 256){
          int t = tt + rot; if (t >= GROUPS) t -= GROUPS;
          int h = hist[t];
          int g = (h > 0) ? atomicAdd(&p.gcnt[t*GPAD], h) : 0;
          hist[t] = g - prefix[t];
        }
      }
      __syncthreads();
      for (int k = 0; k < EPB/256; k++){
        int i = e0 + k*256 + tid;
        if (i < N_EDGES){
          int s = p.src[i], d = p.dst[i];
          int slot = atomicAdd(&prefix[d >> 6], 1);
          sorted[slot] = (unsigned)((d << 16) | s);
        }
      }
      __syncthreads();
      for (int j = tid; j < nval; j += 256){
        unsigned rec = sorted[j];
        int bin = (int)(rec >> 22);
        int off = hist[bin] + j;
        if (off < GCAP) p.recs[(size_t)bin*GCAP + off] = rec;
      }
    } else {
      // ---- GEMM tile: 16 rows x 256 cols, bf16x3 ----
      constexpr int K = F_IN;
      const int wv   = tid >> 6;
      const int lane = tid & 63;
      const int quad = lane >> 4;
      const int l16  = lane & 15;
      const int m0   = (vb - P1B) * 16;
      constexpr int NC = K / 32;
      float* el_lds = (float*)smem;        // [16][8]
      float* er_lds = el_lds + 128;

      short8 Ah[NC], Al_[NC];
      {
        const float* xrow = p.x + (size_t)(m0 + l16)*K;
        #pragma unroll
        for (int c = 0; c < NC; c++){
          float4 a0 = *(const float4*)(xrow + c*32 + quad*8);
          float4 a1 = *(const float4*)(xrow + c*32 + quad*8 + 4);
          const float vs[8] = {a0.x,a0.y,a0.z,a0.w,a1.x,a1.y,a1.z,a1.w};
          #pragma unroll
          for (int j = 0; j < 8; j++){
            unsigned short hs = f2bf_rne(vs[j]);
            Ah[c][j]  = (short)hs;
            Al_[c][j] = (short)f2bf_rne(vs[j] - bf2f(hs));
          }
        }
      }

      float elp[8], erp[8];
      #pragma unroll
      for (int j = 0; j < 8; j++){ elp[j] = 0.f; erp[j] = 0.f; }

      #pragma unroll
      for (int t = 0; t < 4; t++){
        const int nc = wv*64 + t*16;
        const size_t brow = (size_t)(nc + l16) * K;
        f32x4 acc = {0.f, 0.f, 0.f, 0.f};
        #pragma unroll
        for (int c = 0; c < NC; c++){
          short8 Bh = *(const short8*)(p.W1th + brow + c*32 + quad*8);
          short8 Bl = *(const short8*)(p.W1tl + brow + c*32 + quad*8);
          acc = __builtin_amdgcn_mfma_f32_16x16x32_bf16(Ah[c],  Bh, acc, 0, 0, 0);
          acc = __builtin_amdgcn_mfma_f32_16x16x32_bf16(Ah[c],  Bl, acc, 0, 0, 0);
          acc = __builtin_amdgcn_mfma_f32_16x16x32_bf16(Al_[c], Bh, acc, 0, 0, 0);
        }
        const float alv = p.al1[nc + l16];
        const float arv = p.ar1[nc + l16];
        const int hl = t >> 1;
        #pragma unroll
        for (int r = 0; r < 4; r++){
          float v = acc[r];
          p.feat[(size_t)(m0 + quad*4 + r)*FDIM + nc + l16] = f2bf_rne(v);
          elp[r*2 + hl] = fmaf(v, alv, elp[r*2 + hl]);
          erp[r*2 + hl] = fmaf(v, arv, erp[r*2 + hl]);
        }
      }

      #pragma unroll
      for (int off = 1; off <= 8; off <<= 1){
        #pragma unroll
        for (int j = 0; j < 8; j++){
          elp[j] += __shfl_xor(elp[j], off);
          erp[j] += __shfl_xor(erp[j], off);
        }
      }
      if (l16 == 0){
        #pragma unroll
        for (int r = 0; r < 4; r++){
          #pragma unroll
          for (int hl = 0; hl < 2; hl++){
            el_lds[(quad*4 + r)*8 + wv*2 + hl] = elp[r*2 + hl];
            er_lds[(quad*4 + r)*8 + wv*2 + hl] = erp[r*2 + hl];
          }
        }
      }
      __syncthreads();
      if (tid < 128){
        int row = tid >> 3, h = tid & 7;
        p.el1[(size_t)(m0 + row)*NHEAD + h] = el_lds[row*8 + h];
        p.er1[(size_t)(m0 + row)*NHEAD + h] = er_lds[row*8 + h];
      }
    }
  }
  gg.sync();

  // ---------------- S2: per-group bucket build (all-LDS, sparse flush) ----------------
  for (int vb = blockIdx.x; vb < GROUPS; vb += nb){
    __syncthreads();
    int* lcnt  = (int*)smem;       // 64
    int* lbuck = lcnt + 64;        // 64*CAP (24576 B)
    const int n0 = vb << 6;
    if (tid < 64) lcnt[tid] = 0;
    __syncthreads();

    int m = p.gcnt[vb*GPAD]; if (m > GCAP) m = GCAP;
    for (int r = tid; r < m; r += 256){
      unsigned w = p.recs[(size_t)vb*GCAP + r];
      int d = (int)((w >> 16) & 63);
      int pos = atomicAdd(&lcnt[d], 1);
      if (pos < CAP) lbuck[d*CAP + pos] = (int)(w & 0xFFFFu);
    }
    __syncthreads();

    const int nn = min(64, N_NODES - n0);
    const int d = tid >> 2, j = tid & 3;
    if (d < nn){
      int c = lcnt[d];
      if (j == 0) p.cnt[n0 + d] = c;
      if (c > CAP) c = CAP;
      const int n4 = (c + 3) >> 2;
      int4* gb = (int4*)(p.bucket + (size_t)(n0 + d)*CAP);
      const int4* lb = (const int4*)(lbuck + d*CAP);
      for (int i = j; i < n4; i += 4) gb[i] = lb[i];
    }
  }
  gg.sync();

  // ---------------- S3: layer-1 softmax+aggregate (wave-per-node, no block syncs) ----------------
  {
    const int wv   = tid >> 6;
    const int lane = tid & 63;
    char* wb = smem + wv*5056;              // per-wave slab (wave-private, wave-serial)
    float* t_w   = (float*)wb;              // 864 floats
    int*   s_w   = (int*)(wb + 3456);       // 96
    float* sum_h = (float*)(wb + 3840);     // 8
    float* v_sh  = (float*)(wb + 3872);     // 256
    float* h_sh  = (float*)(wb + 4896);     // 32

    for (int vb = blockIdx.x; vb < L1T; vb += nb){
      const int n = vb*4 + wv;
      int C = p.cnt[n];
      if (C > CAP) C = CAP;

      const float4* er4 = (const float4*)(p.er1 + (size_t)n*NHEAD);
      float4 era = er4[0], erb = er4[1];
      const float erv[8] = {era.x, era.y, era.z, era.w, erb.x, erb.y, erb.z, erb.w};

      for (int idx = lane; idx < C*2; idx += 64){
        const int e = idx >> 1, j = idx & 1;
        const int sidx = p.bucket[(size_t)n*CAP + e];
        if (j == 0) s_w[e] = sidx;
        float4 a = ((const float4*)(p.el1 + (size_t)sidx*NHEAD))[j];
        const float ev[4] = {a.x, a.y, a.z, a.w};
        #pragma unroll
        for (int hh = 0; hh < 4; hh++){
          float v = ev[hh] + erv[j*4 + hh];
          t_w[e*9 + j*4 + hh] = (v > 0.f) ? v : 0.2f*v;
        }
      }
      {
        const int h = lane >> 3, d = lane & 7;
        float lm = -INFINITY;
        for (int e = d; e < C; e += 8) lm = fmaxf(lm, t_w[e*9 + h]);
        #pragma unroll
        for (int off = 4; off >= 1; off >>= 1) lm = fmaxf(lm, __shfl_xor(lm, off));
        float ls = 0.f;
        for (int e = d; e < C; e += 8){
          float ex = __expf(t_w[e*9 + h] - lm);
          t_w[e*9 + h] = ex;
          ls += ex;
        }
        #pragma unroll
        for (int off = 4; off >= 1; off >>= 1) ls += __shfl_xor(ls, off);
        if (d == 0) sum_h[h] = ls;
      }

      const int sub = lane >> 5;
      const int l   = lane & 31;
      const int hB  = l >> 2;
      const int coff = l << 3;
      float acc[8] = {0,0,0,0,0,0,0,0};
      int e = sub;
      float4 fv0, fv1;
      if (e < C)     fv0 = *(const float4*)((const bf16*)p.feat + (size_t)s_w[e]*FDIM + coff);
      if (e + 2 < C) fv1 = *(const float4*)((const bf16*)p.feat + (size_t)s_w[e+2]*FDIM + coff);
      while (e < C){
        float4 fnext;
        if (e + 4 < C) fnext = *(const float4*)((const bf16*)p.feat + (size_t)s_w[e+4]*FDIM + coff);
        const float w = t_w[e*9 + hB];
        const unsigned* u = (const unsigned*)&fv0;
        #pragma unroll
        for (int j = 0; j < 4; j++){
          float flo = __uint_as_float(u[j] << 16);
          float fhi = __uint_as_float(u[j] & 0xFFFF0000u);
          acc[2*j]   = fmaf(w, flo, acc[2*j]);
          acc[2*j+1] = fmaf(w, fhi, acc[2*j+1]);
        }
        fv0 = fv1; fv1 = fnext;
        e += 2;
      }
      #pragma unroll
      for (int j = 0; j < 8; j++) acc[j] += __shfl_xor(acc[j], 32);

      if (lane < 32){
        const float s = sum_h[l >> 2];
        const float4* b4 = (const float4*)(p.b1 + coff);
        float4 ba = b4[0], bb = b4[1];
        float bv[8] = {ba.x, ba.y, ba.z, ba.w, bb.x, bb.y, bb.z, bb.w};
        float v[8];
        #pragma unroll
        for (int j = 0; j < 8; j++){
          float val = (C > 0) ? (acc[j] / s) : 0.f;
          val += bv[j];
          val = fmaxf(val, 0.f);
          v[j] = val;
        }
        float4* v4 = (float4*)&v_sh[coff];
        v4[0] = make_float4(v[0], v[1], v[2], v[3]);
        v4[1] = make_float4(v[4], v[5], v[6], v[7]);
      }
      if (lane < 32){
        float hsum = 0.f;
        #pragma unroll
        for (int hh = 0; hh < 8; hh++) hsum += v_sh[hh*32 + lane];
        hsum *= 0.125f;
        p.hbf[(size_t)n*32 + lane] = f2bf_rne(hsum);
        h_sh[lane] = hsum;
      }
      if (lane < 32){
        const int j    = lane & 7;
        const int sel  = (lane >> 3) & 1;
        const int half = lane >> 4;
        const float* qt = sel ? p.q_rt : p.q_lt;
        float pv = 0.f;
        #pragma unroll
        for (int k = 0; k < 16; k++){
          const int kk = half*16 + k;
          pv = fmaf(h_sh[kk], qt[kk*8 + j], pv);
        }
        pv += __shfl_xor(pv, 16);
        if (lane < 8)       p.el2[(size_t)n*NHEAD + j] = pv;
        else if (lane < 16) p.er2[(size_t)n*NHEAD + j] = pv;
      }
    }
  }
  gg.sync();

  // ---------------- S4: layer-2 softmax+aggregate (feat2 never built) ----------------
  {
    const int wv   = tid >> 6;
    const int lane = tid & 63;
    float* t_all0  = (float*)smem;                    // 4 slabs x 1152 floats
    float* t_w     = t_all0 + wv*1152;
    int*   s_w     = (int*)(smem + 18432) + wv*96;
    float* sum_all = (float*)(smem + 18432 + 1536);   // [4][8]
    float* sum_w   = sum_all + wv*8;

    for (int vb = blockIdx.x; vb < L1T; vb += nb){
      __syncthreads();   // LDS handoff between loop iterations
      const int n = vb*4 + wv;
      int C = p.cnt[n];
      if (C > CAP) C = CAP;

      const float4* er4 = (const float4*)(p.er2 + (size_t)n*NHEAD);
      float4 era = er4[0], erb = er4[1];
      const float erv[8] = {era.x, era.y, era.z, era.w, erb.x, erb.y, erb.z, erb.w};

      for (int idx = lane; idx < C*2; idx += 64){
        const int e = idx >> 1, j = idx & 1;
        const int sidx = p.bucket[(size_t)n*CAP + e];
        if (j == 0) s_w[e] = sidx;
        float4 a = ((const float4*)(p.el2 + (size_t)sidx*NHEAD))[j];
        const float ev[4] = {a.x, a.y, a.z, a.w};
        #pragma unroll
        for (int hh = 0; hh < 4; hh++){
          float v = ev[hh] + erv[j*4 + hh];
          t_w[e*TW2 + j*4 + hh] = (v > 0.f) ? v : 0.2f*v;
        }
      }
      {
        const int h = lane >> 3, d = lane & 7;
        float lm = -INFINITY;
        for (int e = d; e < C; e += 8) lm = fmaxf(lm, t_w[e*TW2 + h]);
        #pragma unroll
        for (int off = 4; off >= 1; off >>= 1) lm = fmaxf(lm, __shfl_xor(lm, off));
        float ls = 0.f;
        for (int e = d; e < C; e += 8){
          float ex = __expf(t_w[e*TW2 + h] - lm);
          t_w[e*TW2 + h] = ex;
          ls += ex;
        }
        #pragma unroll
        for (int off = 4; off >= 1; off >>= 1) ls += __shfl_xor(ls, off);
        if (d == 0) sum_w[h] = ls;
      }

      const int sub = lane >> 4;
      const int q   = lane & 15;
      float acc[16];
      #pragma unroll
      for (int i = 0; i < 16; i++) acc[i] = 0.f;
      int e = sub;
      unsigned hv;
      if (e < C) hv = *(const unsigned*)(p.hbf + (size_t)s_w[e]*32 + q*2);
      while (e < C){
        const int en = e + 4;
        unsigned hnext;
        if (en < C) hnext = *(const unsigned*)(p.hbf + (size_t)s_w[en]*32 + q*2);
        f32x4 w0 = *(const f32x4*)&t_w[e*TW2];
        f32x4 w1 = *(const f32x4*)&t_w[e*TW2 + 4];
        const float x0 = __uint_as_float(hv << 16);
        const float x1 = __uint_as_float(hv & 0xFFFF0000u);
        #pragma unroll
        for (int h = 0; h < 4; h++){
          acc[2*h]     = fmaf(w0[h], x0, acc[2*h]);
          acc[2*h+1]   = fmaf(w0[h], x1, acc[2*h+1]);
          acc[8+2*h]   = fmaf(w1[h], x0, acc[8+2*h]);
          acc[8+2*h+1] = fmaf(w1[h], x1, acc[8+2*h+1]);
        }
        hv = hnext;
        e = en;
      }
      #pragma unroll
      for (int i = 0; i < 16; i++){
        acc[i] += __shfl_xor(acc[i], 16);
        acc[i] += __shfl_xor(acc[i], 32);
      }
      if (lane < 16){
        #pragma unroll
        for (int h = 0; h < 8; h++){
          const float s = sum_w[h];
          const float inv = (C > 0) ? (1.f / s) : 0.f;
          t_w[h*33 + 2*lane]     = acc[2*h]   * inv;
          t_w[h*33 + 2*lane + 1] = acc[2*h+1] * inv;
        }
      }
      __syncthreads();   // all 4 waves' A ready

      {
        const int c  = tid;
        const int hc = c >> 5;
        float p0=0.f, p1=0.f, p2=0.f, p3=0.f;
        for (int k = 0; k < F_HID; k++){
          float w = p.W2[(size_t)k*FDIM + c];
          p0 = fmaf(t_all0[0*1152 + hc*33 + k], w, p0);
          p1 = fmaf(t_all0[1*1152 + hc*33 + k], w, p1);
          p2 = fmaf(t_all0[2*1152 + hc*33 + k], w, p2);
          p3 = fmaf(t_all0[3*1152 + hc*33 + k], w, p3);
        }
        t_all0[0*1152 + 512 + c] = p0;
        t_all0[1*1152 + 512 + c] = p1;
        t_all0[2*1152 + 512 + c] = p2;
        t_all0[3*1152 + 512 + c] = p3;
      }
      __syncthreads();
      if (tid < 128){
        const int nn = tid >> 5, d = tid & 31;
        float s = 0.f, bm = 0.f;
        #pragma unroll
        for (int hh = 0; hh < 8; hh++){
          s  += t_all0[nn*1152 + 512 + hh*32 + d];
          bm += p.b2[hh*32 + d];
        }
        p.out[(size_t)(vb*4 + nn)*32 + d] = (s + bm) * 0.125f;
      }
    }
  }
}

extern "C" void kernel_launch(void* const* d_in, const int* in_sizes, int n_in,
                              void* d_out, int out_size, void* d_ws, size_t ws_size,
                              hipStream_t stream)
{
  (void)in_sizes; (void)n_in; (void)out_size; (void)ws_size;

  size_t o = 0;
  char* base = (char*)d_ws;
  auto take = [&](size_t bytes) -> char* {
    char* pp = base + o;
    o += (bytes + 255) & ~(size_t)255;
    return pp;
  };
  unsigned short* feat  = (unsigned short*)take((size_t)N_NODES*FDIM*2);
  float* el1    = (float*)take((size_t)N_NODES*NHEAD*4);
  float* er1    = (float*)take((size_t)N_NODES*NHEAD*4);
  float* el2    = (float*)take((size_t)N_NODES*NHEAD*4);
  float* er2    = (float*)take((size_t)N_NODES*NHEAD*4);
  int*   cnt    = (int*)  take((size_t)N_NODES*4);
  int*   bucket = (int*)  take((size_t)N_NODES*CAP*4);
  unsigned short* hbf  = (unsigned short*)take((size_t)N_NODES*F_HID*2);
  unsigned short* W1th = (unsigned short*)take((size_t)FDIM*F_IN*2);
  unsigned short* W1tl = (unsigned short*)take((size_t)FDIM*F_IN*2);
  float* q_lt   = (float*)take((size_t)F_HID*NHEAD*4);
  float* q_rt   = (float*)take((size_t)F_HID*NHEAD*4);
  int*   gcnt   = (int*)  take((size_t)GROUPS*GPAD*4);
  unsigned* recs = (unsigned*)take((size_t)GROUPS*GCAP*4);

  Prm prm;
  prm.x   = (const float*)d_in[0];
  prm.src = (const int*)  d_in[1];
  prm.dst = (const int*)  d_in[2];
  prm.W1  = (const float*)d_in[3];
  prm.al1 = (const float*)d_in[4];
  prm.ar1 = (const float*)d_in[5];
  prm.b1  = (const float*)d_in[6];
  prm.W2  = (const float*)d_in[7];
  prm.al2 = (const float*)d_in[8];
  prm.ar2 = (const float*)d_in[9];
  prm.b2  = (const float*)d_in[10];
  prm.out = (float*)d_out;
  prm.feat = feat; prm.el1 = el1; prm.er1 = er1; prm.el2 = el2; prm.er2 = er2;
  prm.cnt = cnt; prm.bucket = bucket; prm.hbf = hbf;
  prm.W1th = W1th; prm.W1tl = W1tl; prm.q_lt = q_lt; prm.q_rt = q_rt;
  prm.gcnt = gcnt; prm.recs = recs;

  // grid sized to guaranteed co-residency (cooperative launch validates this)
  static int s_grid = 0;
  if (s_grid == 0){
    int mb = 0;
    if (hipOccupancyMaxActiveBlocksPerMultiprocessor(&mb, gat_coop, 256, 0) != hipSuccess || mb <= 0)
      mb = 4;   // conservative fallback: 24.8KB LDS x4 = 99KB/CU, always fits
    s_grid = mb * 256;          // 256 CUs on MI355X
    if (s_grid > 2048) s_grid = 2048;
  }

  void* args[] = { (void*)&prm };
  hipLaunchCooperativeKernel(gat_coop, dim3(s_grid), dim3(256), args, 0, stream);
}

// Round 7
// 168.829 us; speedup vs baseline: 4.1453x; 4.1453x over previous
//
#include <hip/hip_runtime.h>
#include <hip/hip_bf16.h>

#define N_NODES 20000
#define N_EDGES 320000
#define F_IN    128
#define F_HID   32
#define NHEAD   8
#define FDIM    256   // NHEAD * D (layer-1 feat width)
#define CAP     96    // max in-degree capacity; P(Poisson(16) > 96) ~ 1e-44

// two-level partition params
#define GROUPS  313   // ceil(N_NODES/64): coarse bin = dst>>6 (64 nodes per group)
#define GPAD    16    // gcnt padded to 1 counter per 64B line
#define GCAP    2048  // per-group record capacity
#define EPB     2048  // edges per P1 block (8 per thread)
#define P1B     ((N_EDGES + EPB - 1) / EPB)   // 157

#define TW1     12    // l1 t_w stride (floats): 48B rows, 16B-aligned for b128
#define TW2     12    // l2 t_w stride

typedef __hip_bfloat16 bf16;
typedef __attribute__((ext_vector_type(8))) short short8;
typedef __attribute__((ext_vector_type(4))) float f32x4;

// bf16 round-to-nearest-even on raw bits
__device__ __forceinline__ unsigned short f2bf_rne(float f){
  unsigned u = __float_as_uint(f);
  unsigned r = u + 0x7FFFu + ((u >> 16) & 1u);
  return (unsigned short)(r >> 16);
}
__device__ __forceinline__ float bf2f(unsigned short s){
  return __uint_as_float((unsigned)s << 16);
}

// ---------------- stage 0: init ----------------
__global__ void init_kernel(const float* __restrict__ W1, const float* __restrict__ W2,
                            const float* __restrict__ al2, const float* __restrict__ ar2,
                            int* __restrict__ gcnt,
                            unsigned short* __restrict__ h1, unsigned short* __restrict__ l1,
                            float* __restrict__ q_lt, float* __restrict__ q_rt){
  const int b = blockIdx.x;
  if (b == 0){
    for (int i = threadIdx.x; i < GROUPS*GPAD; i += 256) gcnt[i] = 0;
  } else if (b < 129){
    int i = (b - 1)*256 + threadIdx.x;   // over FDIM*F_IN
    int n = i >> 7, k = i & 127;
    float v = W1[(size_t)k*FDIM + n];
    unsigned short hs = f2bf_rne(v);
    h1[i] = hs;
    l1[i] = f2bf_rne(v - bf2f(hs));
  } else {
    int t = threadIdx.x;            // t = k*8 + hh
    int k = t >> 3, hh = t & 7;
    float sl = 0.f, sr = 0.f;
    #pragma unroll
    for (int d = 0; d < 32; d++){
      float w = W2[(size_t)k*FDIM + hh*32 + d];
      sl = fmaf(w, al2[hh*32 + d], sl);
      sr = fmaf(w, ar2[hh*32 + d], sr);
    }
    q_lt[t] = sl;   // layout [k][hh]
    q_rt[t] = sr;
  }
}

// ---------------- stage 1: P1 edge-partition ∥ MFMA GEMM (fused dispatch) ----------------
// ROUND-4 config (best measured, 170.3us): de-convoyed scatter. Round-6 coop
// counters proved P1 is not critical-path (total VALU work of ALL stages ~46us)
// so the counting-sort variant (round-5, +1.6us) is reverted.
#define GEMMB  (N_NODES / 16)
__global__ __launch_bounds__(256) void gemm_p1_kernel(
    const int* __restrict__ src, const int* __restrict__ dst,
    int* __restrict__ gcnt, unsigned* __restrict__ recs,
    const float* __restrict__ X,
    const unsigned short* __restrict__ Wthi, const unsigned short* __restrict__ Wtlo,
    const float* __restrict__ al, const float* __restrict__ ar,
    unsigned short* __restrict__ feat, float* __restrict__ el, float* __restrict__ er)
{
  const int b = blockIdx.x;
  const int tid = threadIdx.x;

  if (b < P1B){
    // ---- P1: coarse partition ----
    __shared__ int hist[GROUPS];   // pass 1: counts; pass 2: global cursors
    for (int t = tid; t < GROUPS; t += 256) hist[t] = 0;
    __syncthreads();

    unsigned rec[8]; int bin[8]; bool val[8];
    const int e0 = b * EPB;
    #pragma unroll
    for (int k = 0; k < 8; k++){
      int i = e0 + k*256 + tid;            // coalesced per k
      val[k] = (i < N_EDGES);
      if (val[k]){
        int s = src[i];
        int d = dst[i];
        bin[k] = d >> 6;
        rec[k] = (unsigned)(((d & 63) << 16) | s);   // src < 2^16, d_local 6b
        atomicAdd(&hist[bin[k]], 1);       // LDS atomic
      }
    }
    __syncthreads();
    {
      const int rot = (b * 97) % GROUPS;   // de-convoy: each block starts elsewhere
      for (int tt = tid; tt < GROUPS; tt += 256){
        int t = tt + rot; if (t >= GROUPS) t -= GROUPS;
        int h = hist[t];
        hist[t] = (h > 0) ? atomicAdd(&gcnt[t*GPAD], h) : 0;   // 1 line per counter
      }
    }
    __syncthreads();
    #pragma unroll
    for (int k = 0; k < 8; k++){
      if (val[k]){
        int pos = atomicAdd(&hist[bin[k]], 1);          // LDS atomic: unique slot
        if (pos < GCAP) recs[(size_t)bin[k]*GCAP + pos] = rec[k];
      }
    }
    return;
  }

  // ---- GEMM path ----
  constexpr int K = F_IN;
  const int wv   = tid >> 6;
  const int lane = tid & 63;
  const int quad = lane >> 4;
  const int l16  = lane & 15;
  const int m0   = (b - P1B) * 16;
  constexpr int NC = K / 32;

  short8 Ah[NC], Al_[NC];
  {
    const float* xrow = X + (size_t)(m0 + l16)*K;
    #pragma unroll
    for (int c = 0; c < NC; c++){
      float4 a0 = *(const float4*)(xrow + c*32 + quad*8);
      float4 a1 = *(const float4*)(xrow + c*32 + quad*8 + 4);
      const float vs[8] = {a0.x,a0.y,a0.z,a0.w,a1.x,a1.y,a1.z,a1.w};
      #pragma unroll
      for (int j = 0; j < 8; j++){
        unsigned short hs = f2bf_rne(vs[j]);
        Ah[c][j]  = (short)hs;
        Al_[c][j] = (short)f2bf_rne(vs[j] - bf2f(hs));
      }
    }
  }

  float elp[8], erp[8];   // [r*2 + hloc], hloc = tile>>1
  #pragma unroll
  for (int j = 0; j < 8; j++){ elp[j] = 0.f; erp[j] = 0.f; }

  #pragma unroll
  for (int t = 0; t < 4; t++){
    const int nc = wv*64 + t*16;
    const size_t brow = (size_t)(nc + l16) * K;
    f32x4 acc = {0.f, 0.f, 0.f, 0.f};
    #pragma unroll
    for (int c = 0; c < NC; c++){
      short8 Bh = *(const short8*)(Wthi + brow + c*32 + quad*8);
      short8 Bl = *(const short8*)(Wtlo + brow + c*32 + quad*8);
      acc = __builtin_amdgcn_mfma_f32_16x16x32_bf16(Ah[c],  Bh, acc, 0, 0, 0);
      acc = __builtin_amdgcn_mfma_f32_16x16x32_bf16(Ah[c],  Bl, acc, 0, 0, 0);
      acc = __builtin_amdgcn_mfma_f32_16x16x32_bf16(Al_[c], Bh, acc, 0, 0, 0);
    }
    const float alv = al[nc + l16];
    const float arv = ar[nc + l16];
    const int hl = t >> 1;
    #pragma unroll
    for (int r = 0; r < 4; r++){
      float v = acc[r];
      feat[(size_t)(m0 + quad*4 + r)*FDIM + nc + l16] = f2bf_rne(v);
      elp[r*2 + hl] = fmaf(v, alv, elp[r*2 + hl]);
      erp[r*2 + hl] = fmaf(v, arv, erp[r*2 + hl]);
    }
  }

  #pragma unroll
  for (int off = 1; off <= 8; off <<= 1){
    #pragma unroll
    for (int j = 0; j < 8; j++){
      elp[j] += __shfl_xor(elp[j], off);
      erp[j] += __shfl_xor(erp[j], off);
    }
  }
  __shared__ float el_lds[16][8], er_lds[16][8];
  if (l16 == 0){
    #pragma unroll
    for (int r = 0; r < 4; r++){
      #pragma unroll
      for (int hl = 0; hl < 2; hl++){
        el_lds[quad*4 + r][wv*2 + hl] = elp[r*2 + hl];
        er_lds[quad*4 + r][wv*2 + hl] = erp[r*2 + hl];
      }
    }
  }
  __syncthreads();
  if (tid < 128){
    int row = tid >> 3, h = tid & 7;
    el[(size_t)(m0 + row)*NHEAD + h] = el_lds[row][h];
    er[(size_t)(m0 + row)*NHEAD + h] = er_lds[row][h];
  }
}

// ---------------- stage 2: P2 — per-group bucket build, all-LDS ----------------
__global__ __launch_bounds__(256) void bucket_build_kernel(
    const unsigned* __restrict__ recs, const int* __restrict__ gcnt,
    int* __restrict__ cnt, int* __restrict__ bucket)
{
  const int g  = blockIdx.x;
  const int n0 = g << 6;
  __shared__ int lcnt[64];
  __shared__ int lbuck[64*CAP];      // 24 KB
  if (threadIdx.x < 64) lcnt[threadIdx.x] = 0;
  __syncthreads();

  int m = gcnt[g*GPAD]; if (m > GCAP) m = GCAP;
  for (int r = threadIdx.x; r < m; r += 256){
    unsigned w = recs[(size_t)g*GCAP + r];
    int d = (int)((w >> 16) & 63);
    int p = atomicAdd(&lcnt[d], 1);  // LDS atomic
    if (p < CAP) lbuck[d*CAP + p] = (int)(w & 0xFFFFu);
  }
  __syncthreads();

  const int nn = min(64, N_NODES - n0);
  const int d = threadIdx.x >> 2, j = threadIdx.x & 3;
  if (d < nn){
    int c = lcnt[d];
    if (j == 0) cnt[n0 + d] = c;
    if (c > CAP) c = CAP;
    const int n4 = (c + 3) >> 2;
    int4* gb = (int4*)(bucket + (size_t)(n0 + d)*CAP);
    const int4* lb = (const int4*)(lbuck + d*CAP);
    for (int i = j; i < n4; i += 4) gb[i] = lb[i];
  }
}

// ---------------- layer-1 edge softmax + aggregate ----------------
// 1-WAVE BLOCKS (round-3). ROUND-6 REWORK:
//  Phase A: 1 lane per edge, t_w stride 12 (48B, 16B-aligned) -> 2x ds_write_b128
//           instead of 8 scalar writes; softmax reads stay conflict-free
//           (banks 12d+h all distinct over d=0..7).
//  Phase B: QUARTER-wave per edge (16 lanes x 32B), 4 edges concurrent + 2-deep
//           prefetch -> ~8 outstanding loads vs 2 before. The feat gather is a
//           ~500cy latency chain; MLP was the limiter.
__global__ __launch_bounds__(64, 6) void edge_agg_l1(
    const bf16* __restrict__ feat, const float* __restrict__ el,
    const float* __restrict__ er, const int* __restrict__ cnt,
    const int* __restrict__ bucket, const float* __restrict__ bias,
    const float* __restrict__ q_lt, const float* __restrict__ q_rt,
    unsigned short* __restrict__ h_out, float* __restrict__ el2,
    float* __restrict__ er2)
{
  const int lane = threadIdx.x;
  const int n    = blockIdx.x;

  __shared__ __align__(16) float t_w[CAP*TW1];   // 4608 B
  __shared__ int   s_w[CAP];
  __shared__ float sum_h[NHEAD];
  __shared__ float v_sh[256];
  __shared__ float h_sh[32];

  int C = cnt[n];
  if (C > CAP) C = CAP;

  const float4* er4 = (const float4*)(er + (size_t)n*NHEAD);
  float4 era = er4[0], erb = er4[1];
  const float erv[8] = {era.x, era.y, era.z, era.w, erb.x, erb.y, erb.z, erb.w};

  // ---- Phase A: logits, 1 lane per edge, b128 LDS writes ----
  for (int e = lane; e < C; e += 64){
    const int sidx = bucket[(size_t)n*CAP + e];
    s_w[e] = sidx;
    const float4* e4 = (const float4*)(el + (size_t)sidx*NHEAD);
    float4 a = e4[0], bq = e4[1];
    float v[8] = {a.x + erv[0], a.y + erv[1], a.z + erv[2], a.w + erv[3],
                  bq.x + erv[4], bq.y + erv[5], bq.z + erv[6], bq.w + erv[7]};
    #pragma unroll
    for (int hh = 0; hh < 8; hh++) v[hh] = (v[hh] > 0.f) ? v[hh] : 0.2f*v[hh];
    float4* tw4 = (float4*)&t_w[e*TW1];
    tw4[0] = make_float4(v[0], v[1], v[2], v[3]);
    tw4[1] = make_float4(v[4], v[5], v[6], v[7]);
  }
  // per-head max + exp + denominator: 8 lanes per head (wave-synchronous)
  {
    const int h = lane >> 3, d = lane & 7;
    float lm = -INFINITY;
    for (int e = d; e < C; e += 8) lm = fmaxf(lm, t_w[e*TW1 + h]);
    #pragma unroll
    for (int off = 4; off >= 1; off >>= 1) lm = fmaxf(lm, __shfl_xor(lm, off));
    float ls = 0.f;
    for (int e = d; e < C; e += 8){
      float ex = __expf(t_w[e*TW1 + h] - lm);
      t_w[e*TW1 + h] = ex;
      ls += ex;
    }
    #pragma unroll
    for (int off = 4; off >= 1; off >>= 1) ls += __shfl_xor(ls, off);
    if (d == 0) sum_h[h] = ls;
  }

  // ---- Phase B: quarter-wave per edge, 2-deep prefetch (8 loads in flight) ----
  const int sub  = lane >> 4;       // edge slot 0..3
  const int q    = lane & 15;       // cols [16q, 16q+16)
  const int hB   = q >> 1;          // head of this col range
  const int coff = q << 4;          // bf16 col offset
  float acc[16];
  #pragma unroll
  for (int i = 0; i < 16; i++) acc[i] = 0.f;
  int e = sub;
  float4 fa0, fb0, fa1, fb1;
  if (e < C){
    const float4* r = (const float4*)(feat + (size_t)s_w[e]*FDIM + coff);
    fa0 = r[0]; fb0 = r[1];
  }
  if (e + 4 < C){
    const float4* r = (const float4*)(feat + (size_t)s_w[e+4]*FDIM + coff);
    fa1 = r[0]; fb1 = r[1];
  }
  while (e < C){
    float4 na, nb;
    if (e + 8 < C){
      const float4* r = (const float4*)(feat + (size_t)s_w[e+8]*FDIM + coff);
      na = r[0]; nb = r[1];
    }
    const float w = t_w[e*TW1 + hB];
    const unsigned* ua = (const unsigned*)&fa0;
    const unsigned* ub = (const unsigned*)&fb0;
    #pragma unroll
    for (int j = 0; j < 4; j++){
      acc[2*j]      = fmaf(w, __uint_as_float(ua[j] << 16),        acc[2*j]);
      acc[2*j+1]    = fmaf(w, __uint_as_float(ua[j] & 0xFFFF0000u), acc[2*j+1]);
      acc[8+2*j]    = fmaf(w, __uint_as_float(ub[j] << 16),        acc[8+2*j]);
      acc[8+2*j+1]  = fmaf(w, __uint_as_float(ub[j] & 0xFFFF0000u), acc[8+2*j+1]);
    }
    fa0 = fa1; fb0 = fb1; fa1 = na; fb1 = nb;
    e += 4;
  }
  #pragma unroll
  for (int i = 0; i < 16; i++){
    acc[i] += __shfl_xor(acc[i], 16);
    acc[i] += __shfl_xor(acc[i], 32);
  }

  // ---- epilogue: divide, bias, relu -> v_sh (lanes<16, 16 cols each) ----
  if (lane < 16){
    const float s = sum_h[hB];
    const float inv = (C > 0) ? (1.f / s) : 0.f;
    const float4* b4 = (const float4*)(bias + coff);
    float4* v4 = (float4*)&v_sh[coff];
    #pragma unroll
    for (int g = 0; g < 4; g++){
      float4 bv = b4[g];
      float4 ov;
      ov.x = fmaxf(acc[4*g+0]*inv + bv.x, 0.f);
      ov.y = fmaxf(acc[4*g+1]*inv + bv.y, 0.f);
      ov.z = fmaxf(acc[4*g+2]*inv + bv.z, 0.f);
      ov.w = fmaxf(acc[4*g+3]*inv + bv.w, 0.f);
      v4[g] = ov;
    }
  }
  if (lane < 32){
    float hsum = 0.f;
    #pragma unroll
    for (int hh = 0; hh < 8; hh++) hsum += v_sh[hh*32 + lane];
    hsum *= 0.125f;                   // h[n][lane], fp32
    h_out[(size_t)n*32 + lane] = f2bf_rne(hsum);
    h_sh[lane] = hsum;
  }
  // el2/er2 = h . q columns — transposed dot: 32 lanes, one output each
  if (lane < 32){
    const int j    = lane & 7;
    const int sel  = (lane >> 3) & 1;
    const int half = lane >> 4;
    const float* qt = sel ? q_rt : q_lt;
    float p = 0.f;
    #pragma unroll
    for (int k = 0; k < 16; k++){
      const int kk = half*16 + k;
      p = fmaf(h_sh[kk], qt[kk*8 + j], p);
    }
    p += __shfl_xor(p, 16);          // combine k-halves
    if (lane < 8)       el2[(size_t)n*NHEAD + j] = p;
    else if (lane < 16) er2[(size_t)n*NHEAD + j] = p;
  }
}

// ---------------- layer-2 edge softmax + aggregate (feat2 never built) ----------------
// Phase B: quarter-wave per edge (round-2). A_lds/red alias the dead t_w slab
// (round-3): LDS 19.6 KB.
__global__ __launch_bounds__(256, 6) void edge_agg_l2(
    const unsigned short* __restrict__ h_bf, const float* __restrict__ el2,
    const float* __restrict__ er2, const int* __restrict__ cnt,
    const int* __restrict__ bucket, const float* __restrict__ W2,
    const float* __restrict__ b2, float* __restrict__ outp)
{
  const int tid  = threadIdx.x;
  const int wv   = tid >> 6;
  const int lane = tid & 63;
  const int n    = blockIdx.x*4 + wv;

  __shared__ __align__(16) float t_all[4][CAP*TW2];   // 1152 floats per slab
  __shared__ int   s_all[4][CAP];
  __shared__ float sum_all[4][NHEAD];
  float* t_w = t_all[wv];
  int*   s_w = s_all[wv];

  int C = cnt[n];
  if (C > CAP) C = CAP;

  const float4* er4 = (const float4*)(er2 + (size_t)n*NHEAD);
  float4 era = er4[0], erb = er4[1];
  const float erv[8] = {era.x, era.y, era.z, era.w, erb.x, erb.y, erb.z, erb.w};

  // ---- Phase A: logits, 2 lanes per edge ----
  for (int idx = lane; idx < C*2; idx += 64){
    const int e = idx >> 1, j = idx & 1;
    const int sidx = bucket[(size_t)n*CAP + e];
    if (j == 0) s_w[e] = sidx;
    float4 a = ((const float4*)(el2 + (size_t)sidx*NHEAD))[j];
    const float ev[4] = {a.x, a.y, a.z, a.w};
    #pragma unroll
    for (int hh = 0; hh < 4; hh++){
      float v = ev[hh] + erv[j*4 + hh];
      t_w[e*TW2 + j*4 + hh] = (v > 0.f) ? v : 0.2f*v;
    }
  }
  // per-head max + exp + denominator
  {
    const int h = lane >> 3, d = lane & 7;
    float lm = -INFINITY;
    for (int e = d; e < C; e += 8) lm = fmaxf(lm, t_w[e*TW2 + h]);
    #pragma unroll
    for (int off = 4; off >= 1; off >>= 1) lm = fmaxf(lm, __shfl_xor(lm, off));
    float ls = 0.f;
    for (int e = d; e < C; e += 8){
      float ex = __expf(t_w[e*TW2 + h] - lm);
      t_w[e*TW2 + h] = ex;
      ls += ex;
    }
    #pragma unroll
    for (int off = 4; off >= 1; off >>= 1) ls += __shfl_xor(ls, off);
    if (d == 0) sum_all[wv][h] = ls;
  }

  // ---- Phase B: quarter-wave per edge; acc[2h+j] = sum_e w[h]*hrow[2q+j] ----
  const int sub = lane >> 4;        // 4 edges in flight
  const int q   = lane & 15;        // dims 2q, 2q+1
  float acc[16];
  #pragma unroll
  for (int i = 0; i < 16; i++) acc[i] = 0.f;
  int e = sub;
  unsigned hv;
  if (e < C) hv = *(const unsigned*)(h_bf + (size_t)s_w[e]*32 + q*2);
  while (e < C){
    const int en = e + 4;
    unsigned hnext;
    if (en < C) hnext = *(const unsigned*)(h_bf + (size_t)s_w[en]*32 + q*2);
    f32x4 w0 = *(const f32x4*)&t_w[e*TW2];      // heads 0..3 (ds_read_b128)
    f32x4 w1 = *(const f32x4*)&t_w[e*TW2 + 4];  // heads 4..7
    const float x0 = __uint_as_float(hv << 16);
    const float x1 = __uint_as_float(hv & 0xFFFF0000u);
    #pragma unroll
    for (int h = 0; h < 4; h++){
      acc[2*h]   = fmaf(w0[h], x0, acc[2*h]);
      acc[2*h+1] = fmaf(w0[h], x1, acc[2*h+1]);
      acc[8+2*h]   = fmaf(w1[h], x0, acc[8+2*h]);
      acc[8+2*h+1] = fmaf(w1[h], x1, acc[8+2*h+1]);
    }
    hv = hnext;
    e = en;
  }
  #pragma unroll
  for (int i = 0; i < 16; i++){
    acc[i] += __shfl_xor(acc[i], 16);
    acc[i] += __shfl_xor(acc[i], 32);
  }
  // write A into own (now dead) t_w slab
  if (lane < 16){
    #pragma unroll
    for (int h = 0; h < 8; h++){
      const float s = sum_all[wv][h];
      const float inv = (C > 0) ? (1.f / s) : 0.f;
      t_w[h*33 + 2*lane]     = acc[2*h]   * inv;
      t_w[h*33 + 2*lane + 1] = acc[2*h+1] * inv;
    }
  }
  __syncthreads();   // all 4 waves' A ready

  // ---- block-cooperative epilogue: c = tid = h*32+d; coalesced W2[k][c] ----
  {
    const int c  = tid;
    const int hc = c >> 5;
    float p0=0.f, p1=0.f, p2=0.f, p3=0.f;
    for (int k = 0; k < F_HID; k++){
      float w = W2[(size_t)k*FDIM + c];     // 1 KB coalesced per k per block
      p0 = fmaf(t_all[0][hc*33 + k], w, p0);    // LDS broadcast reads (A regions)
      p1 = fmaf(t_all[1][hc*33 + k], w, p1);
      p2 = fmaf(t_all[2][hc*33 + k], w, p2);
      p3 = fmaf(t_all[3][hc*33 + k], w, p3);
    }
    t_all[0][512 + c] = p0;   // red regions (disjoint from A regions)
    t_all[1][512 + c] = p1;
    t_all[2][512 + c] = p2;
    t_all[3][512 + c] = p3;
  }
  __syncthreads();
  if (tid < 128){
    const int nn = tid >> 5, d = tid & 31;
    float s = 0.f, bm = 0.f;
    #pragma unroll
    for (int hh = 0; hh < 8; hh++){
      s  += t_all[nn][512 + hh*32 + d];
      bm += b2[hh*32 + d];
    }
    outp[(size_t)(blockIdx.x*4 + nn)*32 + d] = (s + bm) * 0.125f;
  }
}

extern "C" void kernel_launch(void* const* d_in, const int* in_sizes, int n_in,
                              void* d_out, int out_size, void* d_ws, size_t ws_size,
                              hipStream_t stream)
{
  const float* x   = (const float*)d_in[0];
  const int*   src = (const int*)  d_in[1];
  const int*   dst = (const int*)  d_in[2];
  const float* W1  = (const float*)d_in[3];
  const float* al1 = (const float*)d_in[4];
  const float* ar1 = (const float*)d_in[5];
  const float* b1  = (const float*)d_in[6];
  const float* W2  = (const float*)d_in[7];
  const float* al2 = (const float*)d_in[8];
  const float* ar2 = (const float*)d_in[9];
  const float* b2  = (const float*)d_in[10];
  (void)in_sizes; (void)n_in; (void)out_size; (void)ws_size;

  size_t o = 0;
  char* base = (char*)d_ws;
  auto take = [&](size_t bytes) -> char* {
    char* p = base + o;
    o += (bytes + 255) & ~(size_t)255;
    return p;
  };
  unsigned short* feat  = (unsigned short*)take((size_t)N_NODES*FDIM*2);
  float* el1    = (float*)take((size_t)N_NODES*NHEAD*4);
  float* er1    = (float*)take((size_t)N_NODES*NHEAD*4);
  float* el2    = (float*)take((size_t)N_NODES*NHEAD*4);
  float* er2    = (float*)take((size_t)N_NODES*NHEAD*4);
  int*   cnt    = (int*)  take((size_t)N_NODES*4);
  int*   bucket = (int*)  take((size_t)N_NODES*CAP*4);
  unsigned short* hbf  = (unsigned short*)take((size_t)N_NODES*F_HID*2);
  unsigned short* W1th = (unsigned short*)take((size_t)FDIM*F_IN*2);
  unsigned short* W1tl = (unsigned short*)take((size_t)FDIM*F_IN*2);
  float* q_lt   = (float*)take((size_t)F_HID*NHEAD*4);
  float* q_rt   = (float*)take((size_t)F_HID*NHEAD*4);
  int*   gcnt   = (int*)  take((size_t)GROUPS*GPAD*4);
  unsigned* recs = (unsigned*)take((size_t)GROUPS*GCAP*4);

  // stage 0: gcnt=0 + W1 transpose + q projections
  init_kernel<<<130, 256, 0, stream>>>(
      W1, W2, al2, ar2, gcnt, W1th, W1tl, q_lt, q_rt);

  // stage 1: coarse edge partition ∥ layer-1 GEMM (independent, fused dispatch)
  gemm_p1_kernel<<<P1B + GEMMB, 256, 0, stream>>>(
      src, dst, gcnt, recs, x, W1th, W1tl, al1, ar1, feat, el1, er1);

  // stage 2: per-group LDS bucket build (no global atomics, sparse flush)
  bucket_build_kernel<<<GROUPS, 256, 0, stream>>>(recs, gcnt, cnt, bucket);

  // stage 3: layer-1 softmax + aggregate (1-wave blocks, no barriers)
  edge_agg_l1<<<N_NODES, 64, 0, stream>>>(
      (const bf16*)feat, el1, er1, cnt, bucket, b1, q_lt, q_rt, hbf, el2, er2);

  // stage 4: layer-2 softmax + aggregate (feat2 never materialized)
  edge_agg_l2<<<N_NODES/4, 256, 0, stream>>>(
      hbf, el2, er2, cnt, bucket, W2, b2, (float*)d_out);
}

// Round 8
// 167.706 us; speedup vs baseline: 4.1731x; 1.0067x over previous
//
#include <hip/hip_runtime.h>
#include <hip/hip_bf16.h>

#define N_NODES 20000
#define N_EDGES 320000
#define F_IN    128
#define F_HID   32
#define NHEAD   8
#define FDIM    256   // NHEAD * D (layer-1 feat width)
#define CAP     96    // max in-degree capacity; P(Poisson(16) > 96) ~ 1e-44

// two-level partition params
#define GROUPS  313   // ceil(N_NODES/64): coarse bin = dst>>6 (64 nodes per group)
#define GPAD    16    // gcnt padded to 1 counter per 64B line
#define GCAP    2048  // per-group record capacity
#define EPB     2048  // edges per P1 block (8 per thread)
#define P1B     ((N_EDGES + EPB - 1) / EPB)   // 157

#define TW1     12    // l1 t_w stride (floats): 48B rows, 16B-aligned for b128
#define TW2     12    // l2 t_w stride

typedef __hip_bfloat16 bf16;
typedef __attribute__((ext_vector_type(8))) short short8;
typedef __attribute__((ext_vector_type(4))) float f32x4;

// bf16 round-to-nearest-even on raw bits
__device__ __forceinline__ unsigned short f2bf_rne(float f){
  unsigned u = __float_as_uint(f);
  unsigned r = u + 0x7FFFu + ((u >> 16) & 1u);
  return (unsigned short)(r >> 16);
}
__device__ __forceinline__ float bf2f(unsigned short s){
  return __uint_as_float((unsigned)s << 16);
}

// ---------------- stage 0: init ----------------
__global__ void init_kernel(const float* __restrict__ W1, const float* __restrict__ W2,
                            const float* __restrict__ al2, const float* __restrict__ ar2,
                            int* __restrict__ gcnt,
                            unsigned short* __restrict__ h1, unsigned short* __restrict__ l1,
                            float* __restrict__ q_lt, float* __restrict__ q_rt){
  const int b = blockIdx.x;
  if (b == 0){
    for (int i = threadIdx.x; i < GROUPS*GPAD; i += 256) gcnt[i] = 0;
  } else if (b < 129){
    int i = (b - 1)*256 + threadIdx.x;   // over FDIM*F_IN
    int n = i >> 7, k = i & 127;
    float v = W1[(size_t)k*FDIM + n];
    unsigned short hs = f2bf_rne(v);
    h1[i] = hs;
    l1[i] = f2bf_rne(v - bf2f(hs));
  } else {
    int t = threadIdx.x;            // t = k*8 + hh
    int k = t >> 3, hh = t & 7;
    float sl = 0.f, sr = 0.f;
    #pragma unroll
    for (int d = 0; d < 32; d++){
      float w = W2[(size_t)k*FDIM + hh*32 + d];
      sl = fmaf(w, al2[hh*32 + d], sl);
      sr = fmaf(w, ar2[hh*32 + d], sr);
    }
    q_lt[t] = sl;   // layout [k][hh]
    q_rt[t] = sr;
  }
}

// ---------------- stage 1: P1 edge-partition ∥ MFMA GEMM (fused dispatch) ----------------
#define GEMMB  (N_NODES / 16)
__global__ __launch_bounds__(256) void gemm_p1_kernel(
    const int* __restrict__ src, const int* __restrict__ dst,
    int* __restrict__ gcnt, unsigned* __restrict__ recs,
    const float* __restrict__ X,
    const unsigned short* __restrict__ Wthi, const unsigned short* __restrict__ Wtlo,
    const float* __restrict__ al, const float* __restrict__ ar,
    unsigned short* __restrict__ feat, float* __restrict__ el, float* __restrict__ er)
{
  const int b = blockIdx.x;
  const int tid = threadIdx.x;

  if (b < P1B){
    // ---- P1: coarse partition ----
    __shared__ int hist[GROUPS];   // pass 1: counts; pass 2: global cursors
    for (int t = tid; t < GROUPS; t += 256) hist[t] = 0;
    __syncthreads();

    unsigned rec[8]; int bin[8]; bool val[8];
    const int e0 = b * EPB;
    #pragma unroll
    for (int k = 0; k < 8; k++){
      int i = e0 + k*256 + tid;            // coalesced per k
      val[k] = (i < N_EDGES);
      if (val[k]){
        int s = src[i];
        int d = dst[i];
        bin[k] = d >> 6;
        rec[k] = (unsigned)(((d & 63) << 16) | s);   // src < 2^16, d_local 6b
        atomicAdd(&hist[bin[k]], 1);       // LDS atomic
      }
    }
    __syncthreads();
    {
      const int rot = (b * 97) % GROUPS;   // de-convoy: each block starts elsewhere
      for (int tt = tid; tt < GROUPS; tt += 256){
        int t = tt + rot; if (t >= GROUPS) t -= GROUPS;
        int h = hist[t];
        hist[t] = (h > 0) ? atomicAdd(&gcnt[t*GPAD], h) : 0;   // 1 line per counter
      }
    }
    __syncthreads();
    #pragma unroll
    for (int k = 0; k < 8; k++){
      if (val[k]){
        int pos = atomicAdd(&hist[bin[k]], 1);          // LDS atomic: unique slot
        if (pos < GCAP) recs[(size_t)bin[k]*GCAP + pos] = rec[k];
      }
    }
    return;
  }

  // ---- GEMM path ----
  constexpr int K = F_IN;
  const int wv   = tid >> 6;
  const int lane = tid & 63;
  const int quad = lane >> 4;
  const int l16  = lane & 15;
  const int m0   = (b - P1B) * 16;
  constexpr int NC = K / 32;

  short8 Ah[NC], Al_[NC];
  {
    const float* xrow = X + (size_t)(m0 + l16)*K;
    #pragma unroll
    for (int c = 0; c < NC; c++){
      float4 a0 = *(const float4*)(xrow + c*32 + quad*8);
      float4 a1 = *(const float4*)(xrow + c*32 + quad*8 + 4);
      const float vs[8] = {a0.x,a0.y,a0.z,a0.w,a1.x,a1.y,a1.z,a1.w};
      #pragma unroll
      for (int j = 0; j < 8; j++){
        unsigned short hs = f2bf_rne(vs[j]);
        Ah[c][j]  = (short)hs;
        Al_[c][j] = (short)f2bf_rne(vs[j] - bf2f(hs));
      }
    }
  }

  float elp[8], erp[8];   // [r*2 + hloc], hloc = tile>>1
  #pragma unroll
  for (int j = 0; j < 8; j++){ elp[j] = 0.f; erp[j] = 0.f; }

  #pragma unroll
  for (int t = 0; t < 4; t++){
    const int nc = wv*64 + t*16;
    const size_t brow = (size_t)(nc + l16) * K;
    f32x4 acc = {0.f, 0.f, 0.f, 0.f};
    #pragma unroll
    for (int c = 0; c < NC; c++){
      short8 Bh = *(const short8*)(Wthi + brow + c*32 + quad*8);
      short8 Bl = *(const short8*)(Wtlo + brow + c*32 + quad*8);
      acc = __builtin_amdgcn_mfma_f32_16x16x32_bf16(Ah[c],  Bh, acc, 0, 0, 0);
      acc = __builtin_amdgcn_mfma_f32_16x16x32_bf16(Ah[c],  Bl, acc, 0, 0, 0);
      acc = __builtin_amdgcn_mfma_f32_16x16x32_bf16(Al_[c], Bh, acc, 0, 0, 0);
    }
    const float alv = al[nc + l16];
    const float arv = ar[nc + l16];
    const int hl = t >> 1;
    #pragma unroll
    for (int r = 0; r < 4; r++){
      float v = acc[r];
      feat[(size_t)(m0 + quad*4 + r)*FDIM + nc + l16] = f2bf_rne(v);
      elp[r*2 + hl] = fmaf(v, alv, elp[r*2 + hl]);
      erp[r*2 + hl] = fmaf(v, arv, erp[r*2 + hl]);
    }
  }

  #pragma unroll
  for (int off = 1; off <= 8; off <<= 1){
    #pragma unroll
    for (int j = 0; j < 8; j++){
      elp[j] += __shfl_xor(elp[j], off);
      erp[j] += __shfl_xor(erp[j], off);
    }
  }
  __shared__ float el_lds[16][8], er_lds[16][8];
  if (l16 == 0){
    #pragma unroll
    for (int r = 0; r < 4; r++){
      #pragma unroll
      for (int hl = 0; hl < 2; hl++){
        el_lds[quad*4 + r][wv*2 + hl] = elp[r*2 + hl];
        er_lds[quad*4 + r][wv*2 + hl] = erp[r*2 + hl];
      }
    }
  }
  __syncthreads();
  if (tid < 128){
    int row = tid >> 3, h = tid & 7;
    el[(size_t)(m0 + row)*NHEAD + h] = el_lds[row][h];
    er[(size_t)(m0 + row)*NHEAD + h] = er_lds[row][h];
  }
}

// ---------------- stage 2: P2 — per-group bucket build, all-LDS ----------------
__global__ __launch_bounds__(256) void bucket_build_kernel(
    const unsigned* __restrict__ recs, const int* __restrict__ gcnt,
    int* __restrict__ cnt, int* __restrict__ bucket)
{
  const int g  = blockIdx.x;
  const int n0 = g << 6;
  __shared__ int lcnt[64];
  __shared__ int lbuck[64*CAP];      // 24 KB
  if (threadIdx.x < 64) lcnt[threadIdx.x] = 0;
  __syncthreads();

  int m = gcnt[g*GPAD]; if (m > GCAP) m = GCAP;
  for (int r = threadIdx.x; r < m; r += 256){
    unsigned w = recs[(size_t)g*GCAP + r];
    int d = (int)((w >> 16) & 63);
    int p = atomicAdd(&lcnt[d], 1);  // LDS atomic
    if (p < CAP) lbuck[d*CAP + p] = (int)(w & 0xFFFFu);
  }
  __syncthreads();

  const int nn = min(64, N_NODES - n0);
  const int d = threadIdx.x >> 2, j = threadIdx.x & 3;
  if (d < nn){
    int c = lcnt[d];
    if (j == 0) cnt[n0 + d] = c;
    if (c > CAP) c = CAP;
    const int n4 = (c + 3) >> 2;
    int4* gb = (int4*)(bucket + (size_t)(n0 + d)*CAP);
    const int4* lb = (const int4*)(lbuck + d*CAP);
    for (int i = j; i < n4; i += 4) gb[i] = lb[i];
  }
}

// ---------------- layer-1 edge softmax + aggregate ----------------
// 1-wave blocks; Phase A 1-lane/edge b128 writes; Phase B quarter-wave/edge,
// 2-deep prefetch (round-7 verified, 168.8us best).
__global__ __launch_bounds__(64, 6) void edge_agg_l1(
    const bf16* __restrict__ feat, const float* __restrict__ el,
    const float* __restrict__ er, const int* __restrict__ cnt,
    const int* __restrict__ bucket, const float* __restrict__ bias,
    const float* __restrict__ q_lt, const float* __restrict__ q_rt,
    unsigned short* __restrict__ h_out, float* __restrict__ el2,
    float* __restrict__ er2)
{
  const int lane = threadIdx.x;
  const int n    = blockIdx.x;

  __shared__ __align__(16) float t_w[CAP*TW1];   // 4608 B
  __shared__ int   s_w[CAP];
  __shared__ float sum_h[NHEAD];
  __shared__ float v_sh[256];
  __shared__ float h_sh[32];

  int C = cnt[n];
  if (C > CAP) C = CAP;

  const float4* er4 = (const float4*)(er + (size_t)n*NHEAD);
  float4 era = er4[0], erb = er4[1];
  const float erv[8] = {era.x, era.y, era.z, era.w, erb.x, erb.y, erb.z, erb.w};

  // ---- Phase A: logits, 1 lane per edge, b128 LDS writes ----
  for (int e = lane; e < C; e += 64){
    const int sidx = bucket[(size_t)n*CAP + e];
    s_w[e] = sidx;
    const float4* e4 = (const float4*)(el + (size_t)sidx*NHEAD);
    float4 a = e4[0], bq = e4[1];
    float v[8] = {a.x + erv[0], a.y + erv[1], a.z + erv[2], a.w + erv[3],
                  bq.x + erv[4], bq.y + erv[5], bq.z + erv[6], bq.w + erv[7]};
    #pragma unroll
    for (int hh = 0; hh < 8; hh++) v[hh] = (v[hh] > 0.f) ? v[hh] : 0.2f*v[hh];
    float4* tw4 = (float4*)&t_w[e*TW1];
    tw4[0] = make_float4(v[0], v[1], v[2], v[3]);
    tw4[1] = make_float4(v[4], v[5], v[6], v[7]);
  }
  // per-head max + exp + denominator: 8 lanes per head (wave-synchronous)
  {
    const int h = lane >> 3, d = lane & 7;
    float lm = -INFINITY;
    for (int e = d; e < C; e += 8) lm = fmaxf(lm, t_w[e*TW1 + h]);
    #pragma unroll
    for (int off = 4; off >= 1; off >>= 1) lm = fmaxf(lm, __shfl_xor(lm, off));
    float ls = 0.f;
    for (int e = d; e < C; e += 8){
      float ex = __expf(t_w[e*TW1 + h] - lm);
      t_w[e*TW1 + h] = ex;
      ls += ex;
    }
    #pragma unroll
    for (int off = 4; off >= 1; off >>= 1) ls += __shfl_xor(ls, off);
    if (d == 0) sum_h[h] = ls;
  }

  // ---- Phase B: quarter-wave per edge, 2-deep prefetch (8 loads in flight) ----
  const int sub  = lane >> 4;       // edge slot 0..3
  const int q    = lane & 15;       // cols [16q, 16q+16)
  const int hB   = q >> 1;          // head of this col range
  const int coff = q << 4;          // bf16 col offset
  float acc[16];
  #pragma unroll
  for (int i = 0; i < 16; i++) acc[i] = 0.f;
  int e = sub;
  float4 fa0, fb0, fa1, fb1;
  if (e < C){
    const float4* r = (const float4*)(feat + (size_t)s_w[e]*FDIM + coff);
    fa0 = r[0]; fb0 = r[1];
  }
  if (e + 4 < C){
    const float4* r = (const float4*)(feat + (size_t)s_w[e+4]*FDIM + coff);
    fa1 = r[0]; fb1 = r[1];
  }
  while (e < C){
    float4 na, nb;
    if (e + 8 < C){
      const float4* r = (const float4*)(feat + (size_t)s_w[e+8]*FDIM + coff);
      na = r[0]; nb = r[1];
    }
    const float w = t_w[e*TW1 + hB];
    const unsigned* ua = (const unsigned*)&fa0;
    const unsigned* ub = (const unsigned*)&fb0;
    #pragma unroll
    for (int j = 0; j < 4; j++){
      acc[2*j]      = fmaf(w, __uint_as_float(ua[j] << 16),        acc[2*j]);
      acc[2*j+1]    = fmaf(w, __uint_as_float(ua[j] & 0xFFFF0000u), acc[2*j+1]);
      acc[8+2*j]    = fmaf(w, __uint_as_float(ub[j] << 16),        acc[8+2*j]);
      acc[8+2*j+1]  = fmaf(w, __uint_as_float(ub[j] & 0xFFFF0000u), acc[8+2*j+1]);
    }
    fa0 = fa1; fb0 = fb1; fa1 = na; fb1 = nb;
    e += 4;
  }
  #pragma unroll
  for (int i = 0; i < 16; i++){
    acc[i] += __shfl_xor(acc[i], 16);
    acc[i] += __shfl_xor(acc[i], 32);
  }

  // ---- epilogue: divide, bias, relu -> v_sh (lanes<16, 16 cols each) ----
  if (lane < 16){
    const float s = sum_h[hB];
    const float inv = (C > 0) ? (1.f / s) : 0.f;
    const float4* b4 = (const float4*)(bias + coff);
    float4* v4 = (float4*)&v_sh[coff];
    #pragma unroll
    for (int g = 0; g < 4; g++){
      float4 bv = b4[g];
      float4 ov;
      ov.x = fmaxf(acc[4*g+0]*inv + bv.x, 0.f);
      ov.y = fmaxf(acc[4*g+1]*inv + bv.y, 0.f);
      ov.z = fmaxf(acc[4*g+2]*inv + bv.z, 0.f);
      ov.w = fmaxf(acc[4*g+3]*inv + bv.w, 0.f);
      v4[g] = ov;
    }
  }
  if (lane < 32){
    float hsum = 0.f;
    #pragma unroll
    for (int hh = 0; hh < 8; hh++) hsum += v_sh[hh*32 + lane];
    hsum *= 0.125f;                   // h[n][lane], fp32
    h_out[(size_t)n*32 + lane] = f2bf_rne(hsum);
    h_sh[lane] = hsum;
  }
  // el2/er2 = h . q columns — transposed dot: 32 lanes, one output each
  if (lane < 32){
    const int j    = lane & 7;
    const int sel  = (lane >> 3) & 1;
    const int half = lane >> 4;
    const float* qt = sel ? q_rt : q_lt;
    float p = 0.f;
    #pragma unroll
    for (int k = 0; k < 16; k++){
      const int kk = half*16 + k;
      p = fmaf(h_sh[kk], qt[kk*8 + j], p);
    }
    p += __shfl_xor(p, 16);          // combine k-halves
    if (lane < 8)       el2[(size_t)n*NHEAD + j] = p;
    else if (lane < 16) er2[(size_t)n*NHEAD + j] = p;
  }
}

// ---------------- layer-2 edge softmax + aggregate (feat2 never built) ----------------
// ROUND-8: port l1's verified pattern —
//  Phase A: 1 lane/edge, 2x float4 el2 load + leaky in regs + 2x ds_write_b128
//           (was 2-lane j-split with 8 scalar ds_writes).
//  Phase B: 2-deep prefetch (8 edges in flight; was 1-deep/4).
// A_lds/red alias the dead t_w slab (round-3): LDS 19.6 KB.
__global__ __launch_bounds__(256, 6) void edge_agg_l2(
    const unsigned short* __restrict__ h_bf, const float* __restrict__ el2,
    const float* __restrict__ er2, const int* __restrict__ cnt,
    const int* __restrict__ bucket, const float* __restrict__ W2,
    const float* __restrict__ b2, float* __restrict__ outp)
{
  const int tid  = threadIdx.x;
  const int wv   = tid >> 6;
  const int lane = tid & 63;
  const int n    = blockIdx.x*4 + wv;

  __shared__ __align__(16) float t_all[4][CAP*TW2];   // 1152 floats per slab
  __shared__ int   s_all[4][CAP];
  __shared__ float sum_all[4][NHEAD];
  float* t_w = t_all[wv];
  int*   s_w = s_all[wv];

  int C = cnt[n];
  if (C > CAP) C = CAP;

  const float4* er4 = (const float4*)(er2 + (size_t)n*NHEAD);
  float4 era = er4[0], erb = er4[1];
  const float erv[8] = {era.x, era.y, era.z, era.w, erb.x, erb.y, erb.z, erb.w};

  // ---- Phase A: logits, 1 lane per edge, b128 LDS writes ----
  for (int e = lane; e < C; e += 64){
    const int sidx = bucket[(size_t)n*CAP + e];
    s_w[e] = sidx;
    const float4* e4 = (const float4*)(el2 + (size_t)sidx*NHEAD);
    float4 a = e4[0], bq = e4[1];
    float v[8] = {a.x + erv[0], a.y + erv[1], a.z + erv[2], a.w + erv[3],
                  bq.x + erv[4], bq.y + erv[5], bq.z + erv[6], bq.w + erv[7]};
    #pragma unroll
    for (int hh = 0; hh < 8; hh++) v[hh] = (v[hh] > 0.f) ? v[hh] : 0.2f*v[hh];
    float4* tw4 = (float4*)&t_w[e*TW2];
    tw4[0] = make_float4(v[0], v[1], v[2], v[3]);
    tw4[1] = make_float4(v[4], v[5], v[6], v[7]);
  }
  // per-head max + exp + denominator
  {
    const int h = lane >> 3, d = lane & 7;
    float lm = -INFINITY;
    for (int e = d; e < C; e += 8) lm = fmaxf(lm, t_w[e*TW2 + h]);
    #pragma unroll
    for (int off = 4; off >= 1; off >>= 1) lm = fmaxf(lm, __shfl_xor(lm, off));
    float ls = 0.f;
    for (int e = d; e < C; e += 8){
      float ex = __expf(t_w[e*TW2 + h] - lm);
      t_w[e*TW2 + h] = ex;
      ls += ex;
    }
    #pragma unroll
    for (int off = 4; off >= 1; off >>= 1) ls += __shfl_xor(ls, off);
    if (d == 0) sum_all[wv][h] = ls;
  }

  // ---- Phase B: quarter-wave per edge, 2-deep prefetch ----
  const int sub = lane >> 4;        // 4 edge slots
  const int q   = lane & 15;        // dims 2q, 2q+1
  float acc[16];
  #pragma unroll
  for (int i = 0; i < 16; i++) acc[i] = 0.f;
  int e = sub;
  unsigned hv0, hv1;
  if (e < C)     hv0 = *(const unsigned*)(h_bf + (size_t)s_w[e]*32 + q*2);
  if (e + 4 < C) hv1 = *(const unsigned*)(h_bf + (size_t)s_w[e+4]*32 + q*2);
  while (e < C){
    unsigned hn;
    if (e + 8 < C) hn = *(const unsigned*)(h_bf + (size_t)s_w[e+8]*32 + q*2);
    f32x4 w0 = *(const f32x4*)&t_w[e*TW2];      // heads 0..3 (ds_read_b128)
    f32x4 w1 = *(const f32x4*)&t_w[e*TW2 + 4];  // heads 4..7
    const float x0 = __uint_as_float(hv0 << 16);
    const float x1 = __uint_as_float(hv0 & 0xFFFF0000u);
    #pragma unroll
    for (int h = 0; h < 4; h++){
      acc[2*h]     = fmaf(w0[h], x0, acc[2*h]);
      acc[2*h+1]   = fmaf(w0[h], x1, acc[2*h+1]);
      acc[8+2*h]   = fmaf(w1[h], x0, acc[8+2*h]);
      acc[8+2*h+1] = fmaf(w1[h], x1, acc[8+2*h+1]);
    }
    hv0 = hv1; hv1 = hn;
    e += 4;
  }
  #pragma unroll
  for (int i = 0; i < 16; i++){
    acc[i] += __shfl_xor(acc[i], 16);
    acc[i] += __shfl_xor(acc[i], 32);
  }
  // write A into own (now dead) t_w slab
  if (lane < 16){
    #pragma unroll
    for (int h = 0; h < 8; h++){
      const float s = sum_all[wv][h];
      const float inv = (C > 0) ? (1.f / s) : 0.f;
      t_w[h*33 + 2*lane]     = acc[2*h]   * inv;
      t_w[h*33 + 2*lane + 1] = acc[2*h+1] * inv;
    }
  }
  __syncthreads();   // all 4 waves' A ready

  // ---- block-cooperative epilogue: c = tid = h*32+d; coalesced W2[k][c] ----
  {
    const int c  = tid;
    const int hc = c >> 5;
    float p0=0.f, p1=0.f, p2=0.f, p3=0.f;
    for (int k = 0; k < F_HID; k++){
      float w = W2[(size_t)k*FDIM + c];     // 1 KB coalesced per k per block
      p0 = fmaf(t_all[0][hc*33 + k], w, p0);    // LDS broadcast reads (A regions)
      p1 = fmaf(t_all[1][hc*33 + k], w, p1);
      p2 = fmaf(t_all[2][hc*33 + k], w, p2);
      p3 = fmaf(t_all[3][hc*33 + k], w, p3);
    }
    t_all[0][512 + c] = p0;   // red regions (disjoint from A regions)
    t_all[1][512 + c] = p1;
    t_all[2][512 + c] = p2;
    t_all[3][512 + c] = p3;
  }
  __syncthreads();
  if (tid < 128){
    const int nn = tid >> 5, d = tid & 31;
    float s = 0.f, bm = 0.f;
    #pragma unroll
    for (int hh = 0; hh < 8; hh++){
      s  += t_all[nn][512 + hh*32 + d];
      bm += b2[hh*32 + d];
    }
    outp[(size_t)(blockIdx.x*4 + nn)*32 + d] = (s + bm) * 0.125f;
  }
}

extern "C" void kernel_launch(void* const* d_in, const int* in_sizes, int n_in,
                              void* d_out, int out_size, void* d_ws, size_t ws_size,
                              hipStream_t stream)
{
  const float* x   = (const float*)d_in[0];
  const int*   src = (const int*)  d_in[1];
  const int*   dst = (const int*)  d_in[2];
  const float* W1  = (const float*)d_in[3];
  const float* al1 = (const float*)d_in[4];
  const float* ar1 = (const float*)d_in[5];
  const float* b1  = (const float*)d_in[6];
  const float* W2  = (const float*)d_in[7];
  const float* al2 = (const float*)d_in[8];
  const float* ar2 = (const float*)d_in[9];
  const float* b2  = (const float*)d_in[10];
  (void)in_sizes; (void)n_in; (void)out_size; (void)ws_size;

  size_t o = 0;
  char* base = (char*)d_ws;
  auto take = [&](size_t bytes) -> char* {
    char* p = base + o;
    o += (bytes + 255) & ~(size_t)255;
    return p;
  };
  unsigned short* feat  = (unsigned short*)take((size_t)N_NODES*FDIM*2);
  float* el1    = (float*)take((size_t)N_NODES*NHEAD*4);
  float* er1    = (float*)take((size_t)N_NODES*NHEAD*4);
  float* el2    = (float*)take((size_t)N_NODES*NHEAD*4);
  float* er2    = (float*)take((size_t)N_NODES*NHEAD*4);
  int*   cnt    = (int*)  take((size_t)N_NODES*4);
  int*   bucket = (int*)  take((size_t)N_NODES*CAP*4);
  unsigned short* hbf  = (unsigned short*)take((size_t)N_NODES*F_HID*2);
  unsigned short* W1th = (unsigned short*)take((size_t)FDIM*F_IN*2);
  unsigned short* W1tl = (unsigned short*)take((size_t)FDIM*F_IN*2);
  float* q_lt   = (float*)take((size_t)F_HID*NHEAD*4);
  float* q_rt   = (float*)take((size_t)F_HID*NHEAD*4);
  int*   gcnt   = (int*)  take((size_t)GROUPS*GPAD*4);
  unsigned* recs = (unsigned*)take((size_t)GROUPS*GCAP*4);

  // stage 0: gcnt=0 + W1 transpose + q projections
  init_kernel<<<130, 256, 0, stream>>>(
      W1, W2, al2, ar2, gcnt, W1th, W1tl, q_lt, q_rt);

  // stage 1: coarse edge partition ∥ layer-1 GEMM (independent, fused dispatch)
  gemm_p1_kernel<<<P1B + GEMMB, 256, 0, stream>>>(
      src, dst, gcnt, recs, x, W1th, W1tl, al1, ar1, feat, el1, er1);

  // stage 2: per-group LDS bucket build (no global atomics, sparse flush)
  bucket_build_kernel<<<GROUPS, 256, 0, stream>>>(recs, gcnt, cnt, bucket);

  // stage 3: layer-1 softmax + aggregate (1-wave blocks, no barriers)
  edge_agg_l1<<<N_NODES, 64, 0, stream>>>(
      (const bf16*)feat, el1, er1, cnt, bucket, b1, q_lt, q_rt, hbf, el2, er2);

  // stage 4: layer-2 softmax + aggregate (feat2 never materialized)
  edge_agg_l2<<<N_NODES/4, 256, 0, stream>>>(
      hbf, el2, er2, cnt, bucket, W2, b2, (float*)d_out);
}